// Round 1
// baseline (483.681 us; speedup 1.0000x reference)
//
#include <hip/hip_runtime.h>
#include <math.h>

// Problem constants (from reference): N=8, T=64, A=65536, C=80
#define NB 8
#define TB 64
#define AB 65536
#define CB 80
#define EPSF 1e-6f

#define LOSS_BLOCKS 2048   // 256 per batch
#define LOSS_ITERS  16     // 16 anchors/block/iter * 256 blocks * 16 iters = 65536

// ---------------- workspace layout ----------------
// [0, 4096)        u64   gt_key[N*T]        (zeroed each launch)
// [4096, 4104)     u32   cnt[2]             (zeroed; [0]=assign done-count, [1]=loss)
// [4352, +2MB)     int   code[N*A]          pos->t, neg->-1, ignore->-2
// [+0, +8KB)       float partial_cls[2048]
// [+8KB, +16KB)    float partial_box[2048]
// [+16KB, +24KB)   int   partial_pos[2048]
#define WS_CNT_OFF   4096
#define WS_CODE_OFF  4352
#define WS_PCLS_OFF  (WS_CODE_OFF + NB*AB*4)
#define WS_PBOX_OFF  (WS_PCLS_OFF + LOSS_BLOCKS*4)
#define WS_PPOS_OFF  (WS_PBOX_OFF + LOSS_BLOCKS*4)

// ---------------- kernel A: assignment + (last block) low-quality override ----
// grid: N*A/256 blocks of 256 threads; block = 256 consecutive anchors of one batch.
// Valid GTs (<=24 of 64; rest are zero-padded rows) are ballot-compacted into the
// front of shared memory so the inner loop runs nv (~24) iterations, not 64.
__global__ __launch_bounds__(256) void assign_kernel(
    const float* __restrict__ bbox_true,     // (N,T,4)
    const float* __restrict__ anchors,       // (A,4)
    int*   __restrict__ code,                // (N,A)
    unsigned long long* __restrict__ gt_key, // (N,T)
    unsigned* __restrict__ cnt)              // done-counter (zeroed)
{
    __shared__ float4 s_box[TB];
    __shared__ float  s_a1[TB];
    __shared__ int    s_t[TB];
    __shared__ unsigned long long s_key[TB];
    __shared__ int s_nv;
    __shared__ unsigned s_rank;

    const int blk   = blockIdx.x;
    const int i     = blk >> 8;            // 256 blocks per batch
    const int abase = (blk & 255) << 8;
    const int tid   = threadIdx.x;

    if (tid < TB) {   // exactly wave 0
        float4 b = ((const float4*)bbox_true)[i * TB + tid];
        bool valid = (b.x > 0.f) || (b.y > 0.f) || (b.z > 0.f) || (b.w > 0.f);
        unsigned long long m = __ballot(valid);
        int slot = __popcll(m & ((1ull << tid) - 1ull));  // order-preserving compaction
        if (valid) {
            s_box[slot] = b;
            s_a1[slot]  = fmaxf(b.z - b.x, 0.f) * fmaxf(b.w - b.y, 0.f);
            s_t[slot]   = tid;
        }
        s_key[tid] = 0ull;
        if (tid == 0) s_nv = __popcll(m);
    }
    __syncthreads();

    const int a = abase + tid;
    const float4 an = ((const float4*)anchors)[a];
    const float a2 = fmaxf(an.z - an.x, 0.f) * fmaxf(an.w - an.y, 0.f);
    const unsigned long long inva = (unsigned long long)((unsigned)a ^ 0xFFFFFFFFu);
    const int nv = s_nv;

    float best = -1.0f;
    int bestt = 0;
    #pragma unroll 4
    for (int j = 0; j < nv; ++j) {
        float4 b = s_box[j];
        float lx = fmaxf(b.x, an.x), ly = fmaxf(b.y, an.y);
        float rx = fminf(b.z, an.z), ry = fminf(b.w, an.w);
        float w = fmaxf(rx - lx, 0.f), h = fmaxf(ry - ly, 0.f);
        float inter = w * h;
        float uni = s_a1[j] + a2 - inter;          // exact IEEE div: must match ref argmax/thresholds
        float iou = inter / fmaxf(uni, 1e-10f);
        int t = s_t[j];
        // compaction preserves ascending t => strict > keeps first-max (jnp.argmax tie rule)
        if (iou > best) { best = iou; bestt = t; }
        if (iou > 0.f) {
            // higher iou wins; tie -> smaller anchor index
            unsigned long long key = ((unsigned long long)__float_as_uint(iou) << 32) | inva;
            if (key > s_key[t])   // racy hint; atomic is authoritative
                atomicMax(&s_key[t], key);
        }
    }
    bool pos = best >= 0.5f;
    bool neg = best < 0.4f;   // includes best==-1 (no valid gt)
    code[i * AB + a] = pos ? bestt : (neg ? -1 : -2);

    __syncthreads();
    if (tid < TB) {
        unsigned long long k = s_key[tid];
        if (k) atomicMax(&gt_key[i * TB + tid], k);
    }

    // ---- last-block low-quality override (replaces lq_kernel dispatch) ----
    __threadfence();                       // all threads: flush my code/gt_key writes
    __syncthreads();                       // everyone's fence done
    if (tid == 0) s_rank = atomicAdd(cnt, 1u);
    __syncthreads();
    if (s_rank == gridDim.x - 1) {
        __shared__ unsigned long long sk[NB * TB];
        for (int e = tid; e < NB * TB; e += 256)
            sk[e] = __hip_atomic_load(&gt_key[e], __ATOMIC_RELAXED, __HIP_MEMORY_SCOPE_AGENT);
        __syncthreads();
        // last-gt-wins for duplicate best anchors (matches sequential scatter semantics)
        for (int e = tid; e < NB * TB; e += 256) {
            unsigned long long k = sk[e];
            if (k) {
                int ii = e >> 6, t = e & 63;
                unsigned aa = (unsigned)(k & 0xFFFFFFFFull) ^ 0xFFFFFFFFu;
                bool win = true;
                for (int t2 = t + 1; t2 < TB; ++t2) {
                    unsigned long long k2 = sk[(ii << 6) | t2];
                    if (k2 && (((unsigned)(k2 & 0xFFFFFFFFull) ^ 0xFFFFFFFFu) == aa))
                        win = false;   // a later gt claims the same anchor
                }
                if (win)  // agent-scope store: coherent past non-coherent per-XCD L2s
                    __hip_atomic_store(&code[ii * AB + (int)aa], t,
                                       __ATOMIC_RELAXED, __HIP_MEMORY_SCOPE_AGENT);
            }
        }
    }
}

// ---------------- fast focal / smooth-l1 ----------------
__device__ __forceinline__ float focal1(bool ypos, float l) {
    float q  = __expf(-fabsf(l));                    // v_exp_f32
    float r  = __builtin_amdgcn_rcpf(1.f + q);       // v_rcp_f32
    float lg = __logf(r);                            // v_log_f32; -lg = log1p(q)
    float ce = fmaxf(l, 0.f) - (ypos ? l : 0.f) - lg;
    float p  = (l >= 0.f) ? r : 1.f - r;             // sigmoid(l)
    float pt = ypos ? p : 1.f - p;
    float at = ypos ? 0.25f : 0.75f;
    float om = 1.f - pt;
    return at * om * om * ce;
}
__device__ __forceinline__ float smooth_l1(float x) {
    float d = fabsf(x);
    return d < (1.f / 9.f) ? 4.5f * d * d : d - (0.5f / 9.f);
}

// ---------------- kernel B: loss accumulation + (last block) final reduce ----
// 320 threads = 16 anchors x 20 float4-chunks of 80 classes.
// 2048 blocks (256/batch), 16 grid-stride iterations; per-block partials, no atomics
// on the hot path; last block folds the former reduce_kernel.
__global__ __launch_bounds__(320) void loss_kernel(
    const float* __restrict__ y_true,     // (N,T,C)
    const float* __restrict__ bbox_true,  // (N,T,4)
    const float* __restrict__ y_pred,     // (N,A,C)
    const float* __restrict__ bbox_pred,  // (N,A,4)
    const float* __restrict__ anchors,    // (A,4)
    const int*   __restrict__ code,       // (N,A)
    float* __restrict__ partial_cls,
    float* __restrict__ partial_box,
    int*   __restrict__ partial_pos,
    unsigned* __restrict__ cnt,           // done-counter (zeroed)
    float* __restrict__ out)
{
    const int tid   = threadIdx.x;
    const int la    = tid / 20;       // local anchor 0..15
    const int chunk = tid % 20;       // float4 chunk of classes
    const int blk = blockIdx.x;
    const int i   = blk >> 8;
    const int sub = blk & 255;

    const float4* yp4 = (const float4*)y_pred;
    const float4* yt4 = (const float4*)y_true;

    float cls_acc = 0.f, box_acc = 0.f;
    int posc = 0;

    #pragma unroll 2
    for (int it = 0; it < LOSS_ITERS; ++it) {
        const int a = sub * 16 + la + it * (256 * 16);
        const int g = i * AB + a;
        const int cv = code[g];
        float4 l4 = yp4[g * 20 + chunk];    // hoisted: unconditional, coalesced
        if (cv != -2) {
            bool pos = cv >= 0;
            float y0 = 0.f, y1 = 0.f, y2 = 0.f, y3 = 0.f;
            if (pos) {
                float4 yv = yt4[(i * TB + cv) * 20 + chunk];
                y0 = yv.x; y1 = yv.y; y2 = yv.z; y3 = yv.w;
            }
            cls_acc += focal1(y0 != 0.f, l4.x) + focal1(y1 != 0.f, l4.y) +
                       focal1(y2 != 0.f, l4.z) + focal1(y3 != 0.f, l4.w);
            if (pos && chunk == 0) {
                posc += 1;
                float4 bt = ((const float4*)bbox_true)[i * TB + cv];
                float4 an = ((const float4*)anchors)[a];
                float wa = fmaxf(an.z - an.x, EPSF), ha = fmaxf(an.w - an.y, EPSF);
                float cxa = an.x + 0.5f * wa,  cya = an.y + 0.5f * ha;
                float wt = fmaxf(bt.z - bt.x, EPSF), ht = fmaxf(bt.w - bt.y, EPSF);
                float cxt = bt.x + 0.5f * (bt.z - bt.x), cyt = bt.y + 0.5f * (bt.w - bt.y);
                float d0 = (cxt - cxa) / wa, d1 = (cyt - cya) / ha;
                float d2 = __logf(wt / wa),  d3 = __logf(ht / ha);
                float4 bp = ((const float4*)bbox_pred)[g];
                box_acc += smooth_l1(d0 - bp.x) + smooth_l1(d1 - bp.y) +
                           smooth_l1(d2 - bp.z) + smooth_l1(d3 - bp.w);
            }
        }
    }

    // 64-lane shuffle reduce, then cross-wave via shared, one store per block
    for (int off = 32; off > 0; off >>= 1) {
        cls_acc += __shfl_down(cls_acc, off);
        box_acc += __shfl_down(box_acc, off);
        posc    += __shfl_down(posc, off);
    }
    __shared__ float s_cls[5], s_boxp[5];
    __shared__ int   s_pc[5];
    __shared__ unsigned s_rank;
    const int wave = tid >> 6, lane = tid & 63;
    if (lane == 0) { s_cls[wave] = cls_acc; s_boxp[wave] = box_acc; s_pc[wave] = posc; }
    __syncthreads();
    if (tid == 0) {
        float pc = s_cls[0] + s_cls[1] + s_cls[2] + s_cls[3] + s_cls[4];
        float pb = s_boxp[0] + s_boxp[1] + s_boxp[2] + s_boxp[3] + s_boxp[4];
        int   pp = s_pc[0] + s_pc[1] + s_pc[2] + s_pc[3] + s_pc[4];
        // agent-scope stores: visible past non-coherent per-XCD L2s
        __hip_atomic_store(&partial_cls[blk], pc, __ATOMIC_RELAXED, __HIP_MEMORY_SCOPE_AGENT);
        __hip_atomic_store(&partial_box[blk], pb, __ATOMIC_RELAXED, __HIP_MEMORY_SCOPE_AGENT);
        __hip_atomic_store(&partial_pos[blk], pp, __ATOMIC_RELAXED, __HIP_MEMORY_SCOPE_AGENT);
        __threadfence();
        s_rank = atomicAdd(cnt, 1u);
    }
    __syncthreads();

    // ---- last-block final reduce (replaces reduce_kernel dispatch) ----
    if (s_rank == LOSS_BLOCKS - 1) {
        __threadfence();
        __shared__ float  s_bc[NB];
        __shared__ double sdc[4], sdb[4];
        if (tid < 256) {   // waves 0..3; wave 4 just rides the barriers
            // per-batch positive counts -> avg_factor terms (exact int sums)
            for (int bb = wave; bb < NB; bb += 4) {
                int p = 0;
                #pragma unroll
                for (int j = 0; j < 4; ++j)
                    p += __hip_atomic_load(&partial_pos[bb * 256 + lane + j * 64],
                                           __ATOMIC_RELAXED, __HIP_MEMORY_SCOPE_AGENT);
                for (int off = 32; off > 0; off >>= 1) p += __shfl_down(p, off);
                if (lane == 0) s_bc[bb] = fmaxf((float)p, 1.0f);
            }
            double c = 0.0, bxs = 0.0;
            #pragma unroll
            for (int j = 0; j < 8; ++j) {
                c   += (double)__hip_atomic_load(&partial_cls[tid + j * 256],
                                                 __ATOMIC_RELAXED, __HIP_MEMORY_SCOPE_AGENT);
                bxs += (double)__hip_atomic_load(&partial_box[tid + j * 256],
                                                 __ATOMIC_RELAXED, __HIP_MEMORY_SCOPE_AGENT);
            }
            for (int off = 32; off > 0; off >>= 1) {
                c   += __shfl_down(c, off);
                bxs += __shfl_down(bxs, off);
            }
            if (lane == 0) { sdc[wave] = c; sdb[wave] = bxs; }
        }
        __syncthreads();
        if (tid == 0) {
            double ct = sdc[0] + sdc[1] + sdc[2] + sdc[3];
            double bt = sdb[0] + sdb[1] + sdb[2] + sdb[3];
            float avg = 0.f;
            for (int bb = 0; bb < NB; ++bb) avg += s_bc[bb];  // same order as ref path
            float cf = (float)(ct / (double)avg);
            float bf = (float)(bt / (double)avg);
            if (isnan(cf) || isinf(cf)) cf = 0.f;
            if (isnan(bf) || isinf(bf)) bf = 0.f;
            out[0] = cf;
            out[1] = bf;
        }
    }
}

extern "C" void kernel_launch(void* const* d_in, const int* in_sizes, int n_in,
                              void* d_out, int out_size, void* d_ws, size_t ws_size,
                              hipStream_t stream) {
    const float* y_true    = (const float*)d_in[0];
    const float* bbox_true = (const float*)d_in[1];
    const float* y_pred    = (const float*)d_in[2];
    const float* bbox_pred = (const float*)d_in[3];
    const float* anchors   = (const float*)d_in[4];
    float* out = (float*)d_out;

    char* ws = (char*)d_ws;
    unsigned long long* gt_key = (unsigned long long*)ws;
    unsigned* cnt      = (unsigned*)(ws + WS_CNT_OFF);
    int*   code        = (int*)(ws + WS_CODE_OFF);
    float* partial_cls = (float*)(ws + WS_PCLS_OFF);
    float* partial_box = (float*)(ws + WS_PBOX_OFF);
    int*   partial_pos = (int*)(ws + WS_PPOS_OFF);

    // zero gt_key (atomicMax baseline) + the two done-counters; partials fully overwritten
    hipMemsetAsync(ws, 0, WS_CNT_OFF + 2 * sizeof(unsigned), stream);

    assign_kernel<<<NB * AB / 256, 256, 0, stream>>>(bbox_true, anchors, code, gt_key, cnt);
    loss_kernel<<<LOSS_BLOCKS, 320, 0, stream>>>(
        y_true, bbox_true, y_pred, bbox_pred, anchors, code,
        partial_cls, partial_box, partial_pos, cnt + 1, out);
}

// Round 2
// 293.553 us; speedup vs baseline: 1.6477x; 1.6477x over previous
//
#include <hip/hip_runtime.h>
#include <math.h>

// Problem constants (from reference): N=8, T=64, A=65536, C=80
#define NB 8
#define TB 64
#define AB 65536
#define CB 80
#define EPSF 1e-6f

#define LOSS_BLOCKS 2048   // 256 per batch
#define LOSS_ITERS  16     // 16 anchors/block/iter * 256 blocks * 16 iters = 65536

// ---------------- workspace layout ----------------
// [0, 4096)                u64   gt_key[N*T]            (must be zeroed)
// [4096, 4096+2MB)         int   code[N*A]              pos->t, neg->-1, ignore->-2
// [+0, +8KB)               float partial_cls[2048]
// [+8KB, +16KB)            float partial_box[2048]
// [+16KB, +24KB)           int   partial_pos[2048]
#define WS_CODE_OFF   4096
#define WS_PCLS_OFF   (4096 + NB*AB*4)
#define WS_PBOX_OFF   (WS_PCLS_OFF + LOSS_BLOCKS*4)
#define WS_PPOS_OFF   (WS_PBOX_OFF + LOSS_BLOCKS*4)

// ---------------- kernel A: anchor<->gt assignment ----------------
// grid: N*A/256 blocks of 256 threads; block = 256 consecutive anchors of one batch.
// Valid GTs (<=24 of 64; the rest are zero-padded rows) are ballot-compacted into
// the front of shared memory so the inner loop runs nv (~24) iterations, not 64.
// NOTE (round-1 lesson): NO __threadfence / last-block fusion here — a device-scope
// fence per block is a full L2 writeback on CDNA4 and cost ~190us. Separate
// dispatches provide cross-XCD coherence for free.
__global__ __launch_bounds__(256) void assign_kernel(
    const float* __restrict__ bbox_true,     // (N,T,4)
    const float* __restrict__ anchors,       // (A,4)
    int*   __restrict__ code,                // (N,A)
    unsigned long long* __restrict__ gt_key) // (N,T)
{
    __shared__ float4 s_box[TB];
    __shared__ float  s_a1[TB];
    __shared__ int    s_t[TB];
    __shared__ unsigned long long s_key[TB];
    __shared__ int s_nv;

    const int blk   = blockIdx.x;
    const int i     = blk >> 8;            // 256 blocks per batch
    const int abase = (blk & 255) << 8;
    const int tid   = threadIdx.x;

    if (tid < TB) {   // exactly wave 0
        float4 b = ((const float4*)bbox_true)[i * TB + tid];
        bool valid = (b.x > 0.f) || (b.y > 0.f) || (b.z > 0.f) || (b.w > 0.f);
        unsigned long long m = __ballot(valid);
        int slot = __popcll(m & ((1ull << tid) - 1ull));  // order-preserving compaction
        if (valid) {
            s_box[slot] = b;
            s_a1[slot]  = fmaxf(b.z - b.x, 0.f) * fmaxf(b.w - b.y, 0.f);
            s_t[slot]   = tid;
        }
        s_key[tid] = 0ull;
        if (tid == 0) s_nv = __popcll(m);
    }
    __syncthreads();

    const int a = abase + tid;
    const float4 an = ((const float4*)anchors)[a];
    const float a2 = fmaxf(an.z - an.x, 0.f) * fmaxf(an.w - an.y, 0.f);
    const unsigned long long inva = (unsigned long long)((unsigned)a ^ 0xFFFFFFFFu);
    const int nv = s_nv;

    float best = -1.0f;
    int bestt = 0;
    #pragma unroll 4
    for (int j = 0; j < nv; ++j) {
        float4 b = s_box[j];
        float lx = fmaxf(b.x, an.x), ly = fmaxf(b.y, an.y);
        float rx = fminf(b.z, an.z), ry = fminf(b.w, an.w);
        float w = fmaxf(rx - lx, 0.f), h = fmaxf(ry - ly, 0.f);
        float inter = w * h;
        float uni = s_a1[j] + a2 - inter;          // exact IEEE div: must match ref argmax/thresholds
        float iou = inter / fmaxf(uni, 1e-10f);
        int t = s_t[j];
        // compaction preserves ascending t => strict > keeps first-max (jnp.argmax tie rule)
        if (iou > best) { best = iou; bestt = t; }
        if (iou > 0.f) {
            // higher iou wins; tie -> smaller anchor index
            unsigned long long key = ((unsigned long long)__float_as_uint(iou) << 32) | inva;
            if (key > s_key[t])   // racy hint; atomic is authoritative
                atomicMax(&s_key[t], key);
        }
    }
    bool pos = best >= 0.5f;
    bool neg = best < 0.4f;   // includes best==-1 (no valid gt)
    code[i * AB + a] = pos ? bestt : (neg ? -1 : -2);

    __syncthreads();
    if (tid < TB) {
        unsigned long long k = s_key[tid];
        if (k) atomicMax(&gt_key[i * TB + tid], k);
    }
}

// ---------------- kernel B: low-quality match override ----------------
// 512 threads = 8 batches x 64 gts. last-gt-wins for duplicate best anchors
// (matches the sequential scatter semantics the reference uses).
__global__ void lq_kernel(const unsigned long long* __restrict__ gt_key,
                          int* __restrict__ code)
{
    __shared__ unsigned long long sk[NB * TB];
    const int tid = threadIdx.x;
    sk[tid] = gt_key[tid];
    __syncthreads();
    const int i = tid >> 6, t = tid & 63;
    unsigned long long k = sk[tid];
    if (k) {
        unsigned a = (unsigned)(k & 0xFFFFFFFFull) ^ 0xFFFFFFFFu;
        bool win = true;
        for (int t2 = t + 1; t2 < TB; ++t2) {
            unsigned long long k2 = sk[(i << 6) | t2];
            if (k2 && (((unsigned)(k2 & 0xFFFFFFFFull) ^ 0xFFFFFFFFu) == a))
                win = false;  // a later gt claims the same anchor
        }
        if (win) code[i * AB + (int)a] = t;   // force positive, assigned = t
    }
}

// ---------------- fast focal / smooth-l1 ----------------
// threshold is 35.84 on O(1e3) outputs -> native transcendentals are plenty.
__device__ __forceinline__ float focal1(bool ypos, float l) {
    float q  = __expf(-fabsf(l));                    // v_exp_f32
    float r  = __builtin_amdgcn_rcpf(1.f + q);       // v_rcp_f32
    float lg = __logf(r);                            // v_log_f32; -lg = log1p(q)
    float ce = fmaxf(l, 0.f) - (ypos ? l : 0.f) - lg;
    float p  = (l >= 0.f) ? r : 1.f - r;             // sigmoid(l)
    float pt = ypos ? p : 1.f - p;
    float at = ypos ? 0.25f : 0.75f;
    float om = 1.f - pt;
    return at * om * om * ce;
}
__device__ __forceinline__ float smooth_l1(float x) {
    float d = fabsf(x);
    return d < (1.f / 9.f) ? 4.5f * d * d : d - (0.5f / 9.f);
}

// ---------------- kernel C: loss accumulation ----------------
// 320 threads = 16 anchors x 20 float4-chunks of 80 classes.
// 2048 blocks (256/batch), 16 grid-stride iterations; per-block partials, NO atomics.
// unroll 4 (was 2): VGPR=32 leaves headroom; doubles outstanding y_pred loads.
__global__ __launch_bounds__(320) void loss_kernel(
    const float* __restrict__ y_true,     // (N,T,C)
    const float* __restrict__ bbox_true,  // (N,T,4)
    const float* __restrict__ y_pred,     // (N,A,C)
    const float* __restrict__ bbox_pred,  // (N,A,4)
    const float* __restrict__ anchors,    // (A,4)
    const int*   __restrict__ code,       // (N,A)
    float* __restrict__ partial_cls,
    float* __restrict__ partial_box,
    int*   __restrict__ partial_pos)
{
    const int tid   = threadIdx.x;
    const int la    = tid / 20;       // local anchor 0..15
    const int chunk = tid % 20;       // float4 chunk of classes
    const int b   = blockIdx.x;
    const int i   = b >> 8;
    const int sub = b & 255;

    const float4* yp4 = (const float4*)y_pred;
    const float4* yt4 = (const float4*)y_true;

    float cls_acc = 0.f, box_acc = 0.f;
    int posc = 0;

    #pragma unroll 4
    for (int it = 0; it < LOSS_ITERS; ++it) {
        const int a = sub * 16 + la + it * (256 * 16);
        const int g = i * AB + a;
        const int cv = code[g];
        float4 l4 = yp4[g * 20 + chunk];    // hoisted: unconditional, coalesced
        if (cv != -2) {
            bool pos = cv >= 0;
            float y0 = 0.f, y1 = 0.f, y2 = 0.f, y3 = 0.f;
            if (pos) {
                float4 yv = yt4[(i * TB + cv) * 20 + chunk];
                y0 = yv.x; y1 = yv.y; y2 = yv.z; y3 = yv.w;
            }
            cls_acc += focal1(y0 != 0.f, l4.x) + focal1(y1 != 0.f, l4.y) +
                       focal1(y2 != 0.f, l4.z) + focal1(y3 != 0.f, l4.w);
            if (pos && chunk == 0) {
                posc += 1;
                float4 bt = ((const float4*)bbox_true)[i * TB + cv];
                float4 an = ((const float4*)anchors)[a];
                float wa = fmaxf(an.z - an.x, EPSF), ha = fmaxf(an.w - an.y, EPSF);
                float cxa = an.x + 0.5f * wa,  cya = an.y + 0.5f * ha;
                float wt = fmaxf(bt.z - bt.x, EPSF), ht = fmaxf(bt.w - bt.y, EPSF);
                float cxt = bt.x + 0.5f * (bt.z - bt.x), cyt = bt.y + 0.5f * (bt.w - bt.y);
                float d0 = (cxt - cxa) / wa, d1 = (cyt - cya) / ha;
                float d2 = __logf(wt / wa),  d3 = __logf(ht / ha);
                float4 bp = ((const float4*)bbox_pred)[g];
                box_acc += smooth_l1(d0 - bp.x) + smooth_l1(d1 - bp.y) +
                           smooth_l1(d2 - bp.z) + smooth_l1(d3 - bp.w);
            }
        }
    }

    // 64-lane shuffle reduce, then cross-wave via shared, one store per block
    for (int off = 32; off > 0; off >>= 1) {
        cls_acc += __shfl_down(cls_acc, off);
        box_acc += __shfl_down(box_acc, off);
        posc    += __shfl_down(posc, off);
    }
    __shared__ float s_cls[5], s_box[5];
    __shared__ int   s_pc[5];
    int wave = tid >> 6, lane = tid & 63;
    if (lane == 0) { s_cls[wave] = cls_acc; s_box[wave] = box_acc; s_pc[wave] = posc; }
    __syncthreads();
    if (tid == 0) {
        partial_cls[b] = s_cls[0] + s_cls[1] + s_cls[2] + s_cls[3] + s_cls[4];
        partial_box[b] = s_box[0] + s_box[1] + s_box[2] + s_box[3] + s_box[4];
        partial_pos[b] = s_pc[0] + s_pc[1] + s_pc[2] + s_pc[3] + s_pc[4];
    }
}

// ---------------- kernel D: final reduce + divide + sanitize ----------------
// one block, 256 threads. 2048 partials; pos counts are per-batch (256 blocks/batch).
__global__ __launch_bounds__(256) void reduce_kernel(
    const float* __restrict__ partial_cls,
    const float* __restrict__ partial_box,
    const int*   __restrict__ partial_pos,
    float* __restrict__ out)
{
    const int tid = threadIdx.x;
    const int wave = tid >> 6, lane = tid & 63;
    __shared__ double sc[4], sb[4];
    __shared__ int    si[4];
    __shared__ float  s_avg;

    double c = 0.0, bx = 0.0;
    #pragma unroll
    for (int j = 0; j < LOSS_BLOCKS / 256; ++j) {
        c  += (double)partial_cls[tid + j * 256];
        bx += (double)partial_box[tid + j * 256];
    }

    // per-batch positive counts -> avg_factor
    float avg = 0.f;
    for (int bb = 0; bb < NB; ++bb) {
        int p = partial_pos[bb * 256 + tid];
        for (int off = 32; off > 0; off >>= 1) p += __shfl_down(p, off);
        if (lane == 0) si[wave] = p;
        __syncthreads();
        if (tid == 0) {
            int tot = si[0] + si[1] + si[2] + si[3];
            avg += fmaxf((float)tot, 1.0f);
        }
        __syncthreads();
    }
    if (tid == 0) s_avg = avg;

    for (int off = 32; off > 0; off >>= 1) {
        c  += __shfl_down(c, off);
        bx += __shfl_down(bx, off);
    }
    if (lane == 0) { sc[wave] = c; sb[wave] = bx; }
    __syncthreads();
    if (tid == 0) {
        double ct = sc[0] + sc[1] + sc[2] + sc[3];
        double bt = sb[0] + sb[1] + sb[2] + sb[3];
        float cf = (float)(ct / (double)s_avg);
        float bf = (float)(bt / (double)s_avg);
        if (isnan(cf) || isinf(cf)) cf = 0.f;
        if (isnan(bf) || isinf(bf)) bf = 0.f;
        out[0] = cf;
        out[1] = bf;
    }
}

extern "C" void kernel_launch(void* const* d_in, const int* in_sizes, int n_in,
                              void* d_out, int out_size, void* d_ws, size_t ws_size,
                              hipStream_t stream) {
    const float* y_true    = (const float*)d_in[0];
    const float* bbox_true = (const float*)d_in[1];
    const float* y_pred    = (const float*)d_in[2];
    const float* bbox_pred = (const float*)d_in[3];
    const float* anchors   = (const float*)d_in[4];
    float* out = (float*)d_out;

    char* ws = (char*)d_ws;
    unsigned long long* gt_key = (unsigned long long*)ws;
    int*   code        = (int*)(ws + WS_CODE_OFF);
    float* partial_cls = (float*)(ws + WS_PCLS_OFF);
    float* partial_box = (float*)(ws + WS_PBOX_OFF);
    int*   partial_pos = (int*)(ws + WS_PPOS_OFF);

    // zero only gt_key (atomicMax baseline); partials are fully overwritten
    hipMemsetAsync(ws, 0, NB * TB * sizeof(unsigned long long), stream);

    assign_kernel<<<NB * AB / 256, 256, 0, stream>>>(bbox_true, anchors, code, gt_key);
    lq_kernel<<<1, NB * TB, 0, stream>>>(gt_key, code);
    loss_kernel<<<LOSS_BLOCKS, 320, 0, stream>>>(
        y_true, bbox_true, y_pred, bbox_pred, anchors, code,
        partial_cls, partial_box, partial_pos);
    reduce_kernel<<<1, 256, 0, stream>>>(partial_cls, partial_box, partial_pos, out);
}

// Round 3
// 292.258 us; speedup vs baseline: 1.6550x; 1.0044x over previous
//
#include <hip/hip_runtime.h>
#include <math.h>

// Problem constants (from reference): N=8, T=64, A=65536, C=80
#define NB 8
#define TB 64
#define AB 65536
#define CB 80
#define EPSF 1e-6f

#define LOSS_BLOCKS 2048   // 256 per batch
#define LOSS_ITERS  16     // 16 anchors/block/iter * 256 blocks * 16 iters = 65536

typedef float f32x4 __attribute__((ext_vector_type(4)));

// ---------------- workspace layout ----------------
// [0, 4096)                u64   gt_key[N*T]            (must be zeroed)
// [4096, 4096+2MB)         int   code[N*A]              pos->t, neg->-1, ignore->-2
// [+0, +8KB)               float partial_cls[2048]
// [+8KB, +16KB)            float partial_box[2048]
// [+16KB, +24KB)           int   partial_pos[2048]
#define WS_CODE_OFF   4096
#define WS_PCLS_OFF   (4096 + NB*AB*4)
#define WS_PBOX_OFF   (WS_PCLS_OFF + LOSS_BLOCKS*4)
#define WS_PPOS_OFF   (WS_PBOX_OFF + LOSS_BLOCKS*4)

// ---------------- kernel A: anchor<->gt assignment ----------------
// grid: N*A/256 blocks of 256 threads; block = 256 consecutive anchors of one batch.
// Valid GTs (<=24 of 64; the rest are zero-padded rows) are ballot-compacted into
// the front of shared memory so the inner loop runs nv (~24) iterations, not 64.
// NOTE (round-1 lesson): NO __threadfence / last-block fusion — a device-scope fence
// per block is a full L2 writeback on CDNA4 (cost ~190us). Dispatch boundaries
// provide cross-XCD coherence for free.
__global__ __launch_bounds__(256) void assign_kernel(
    const float* __restrict__ bbox_true,     // (N,T,4)
    const float* __restrict__ anchors,       // (A,4)
    int*   __restrict__ code,                // (N,A)
    unsigned long long* __restrict__ gt_key) // (N,T)
{
    __shared__ float4 s_box[TB];
    __shared__ float  s_a1[TB];
    __shared__ int    s_t[TB];
    __shared__ unsigned long long s_key[TB];
    __shared__ int s_nv;

    const int blk   = blockIdx.x;
    const int i     = blk >> 8;            // 256 blocks per batch
    const int abase = (blk & 255) << 8;
    const int tid   = threadIdx.x;

    if (tid < TB) {   // exactly wave 0
        float4 b = ((const float4*)bbox_true)[i * TB + tid];
        bool valid = (b.x > 0.f) || (b.y > 0.f) || (b.z > 0.f) || (b.w > 0.f);
        unsigned long long m = __ballot(valid);
        int slot = __popcll(m & ((1ull << tid) - 1ull));  // order-preserving compaction
        if (valid) {
            s_box[slot] = b;
            s_a1[slot]  = fmaxf(b.z - b.x, 0.f) * fmaxf(b.w - b.y, 0.f);
            s_t[slot]   = tid;
        }
        s_key[tid] = 0ull;
        if (tid == 0) s_nv = __popcll(m);
    }
    __syncthreads();

    const int a = abase + tid;
    const float4 an = ((const float4*)anchors)[a];
    const float a2 = fmaxf(an.z - an.x, 0.f) * fmaxf(an.w - an.y, 0.f);
    const unsigned long long inva = (unsigned long long)((unsigned)a ^ 0xFFFFFFFFu);
    const int nv = s_nv;

    float best = -1.0f;
    int bestt = 0;
    #pragma unroll 4
    for (int j = 0; j < nv; ++j) {
        float4 b = s_box[j];
        float lx = fmaxf(b.x, an.x), ly = fmaxf(b.y, an.y);
        float rx = fminf(b.z, an.z), ry = fminf(b.w, an.w);
        float w = fmaxf(rx - lx, 0.f), h = fmaxf(ry - ly, 0.f);
        float inter = w * h;
        float uni = s_a1[j] + a2 - inter;          // exact IEEE div: must match ref argmax/thresholds
        float iou = inter / fmaxf(uni, 1e-10f);
        int t = s_t[j];
        // compaction preserves ascending t => strict > keeps first-max (jnp.argmax tie rule)
        if (iou > best) { best = iou; bestt = t; }
        if (iou > 0.f) {
            // higher iou wins; tie -> smaller anchor index
            unsigned long long key = ((unsigned long long)__float_as_uint(iou) << 32) | inva;
            if (key > s_key[t])   // racy hint; atomic is authoritative
                atomicMax(&s_key[t], key);
        }
    }
    bool pos = best >= 0.5f;
    bool neg = best < 0.4f;   // includes best==-1 (no valid gt)
    code[i * AB + a] = pos ? bestt : (neg ? -1 : -2);

    __syncthreads();
    if (tid < TB) {
        unsigned long long k = s_key[tid];
        if (k) atomicMax(&gt_key[i * TB + tid], k);
    }
}

// ---------------- fast focal / smooth-l1 ----------------
// threshold is 35.84 on O(1e3) outputs -> native transcendentals are plenty.
__device__ __forceinline__ float focal1(bool ypos, float l) {
    float q  = __expf(-fabsf(l));                    // v_exp_f32
    float r  = __builtin_amdgcn_rcpf(1.f + q);       // v_rcp_f32
    float lg = __logf(r);                            // v_log_f32; -lg = log1p(q)
    float ce = fmaxf(l, 0.f) - (ypos ? l : 0.f) - lg;
    float p  = (l >= 0.f) ? r : 1.f - r;             // sigmoid(l)
    float pt = ypos ? p : 1.f - p;
    float at = ypos ? 0.25f : 0.75f;
    float om = 1.f - pt;
    return at * om * om * ce;
}
__device__ __forceinline__ float smooth_l1(float x) {
    float d = fabsf(x);
    return d < (1.f / 9.f) ? 4.5f * d * d : d - (0.5f / 9.f);
}

// ---------------- kernel B: loss accumulation (lq override folded in) ----------
// 320 threads = 16 anchors x 20 float4-chunks of 80 classes.
// 2048 blocks (256/batch), 16 grid-stride iterations; per-block partials, NO atomics
// on the hot path.
// The low-quality override (formerly lq_kernel) is applied via a 256-entry LDS
// table built from gt_key: for each valid gt t (ascending), its best anchor gets
// assigned=t, pos=True. LDS atomicMax over t == last-gt-wins scatter semantics.
// gt_key crosses the assign->loss dispatch boundary, so no fences are needed.
__global__ __launch_bounds__(320) void loss_kernel(
    const float* __restrict__ y_true,     // (N,T,C)
    const float* __restrict__ bbox_true,  // (N,T,4)
    const float* __restrict__ y_pred,     // (N,A,C)
    const float* __restrict__ bbox_pred,  // (N,A,4)
    const float* __restrict__ anchors,    // (A,4)
    const int*   __restrict__ code,       // (N,A)
    const unsigned long long* __restrict__ gt_key, // (N,T)
    float* __restrict__ partial_cls,
    float* __restrict__ partial_box,
    int*   __restrict__ partial_pos)
{
    const int tid   = threadIdx.x;
    const int la    = tid / 20;       // local anchor 0..15
    const int chunk = tid % 20;       // float4 chunk of classes
    const int b   = blockIdx.x;
    const int i   = b >> 8;
    const int sub = b & 255;

    // ---- lq override table: slot = it*16 + la for anchor a = it*4096 + sub*16 + la
    __shared__ int s_ov[256];
    if (tid < 256) s_ov[tid] = -1;
    __syncthreads();
    if (tid < TB) {   // wave 0, coalesced 64-lane read of this batch's gt keys
        unsigned long long k = gt_key[i * TB + tid];
        if (k) {
            unsigned aa = (unsigned)(k & 0xFFFFFFFFull) ^ 0xFFFFFFFFu;
            if (((aa >> 4) & 255u) == (unsigned)sub)          // anchor lands in this block
                atomicMax(&s_ov[((aa >> 12) << 4) | (aa & 15u)], tid); // larger t wins
        }
    }
    __syncthreads();

    const f32x4* yp4 = (const f32x4*)y_pred;
    const float4* yt4 = (const float4*)y_true;

    float cls_acc = 0.f, box_acc = 0.f;
    int posc = 0;

    #pragma unroll 4
    for (int it = 0; it < LOSS_ITERS; ++it) {
        const int a = sub * 16 + la + it * (256 * 16);
        const int g = i * AB + a;
        int cv = code[g];
        const int ov = s_ov[it * 16 + la];
        if (ov >= 0) cv = ov;               // lq override: force positive, assigned=ov
        // hoisted unconditional coalesced stream; nt: no reuse, keep L2 for code/y_true
        f32x4 l4 = __builtin_nontemporal_load(&yp4[g * 20 + chunk]);
        if (cv != -2) {
            bool pos = cv >= 0;
            float y0 = 0.f, y1 = 0.f, y2 = 0.f, y3 = 0.f;
            if (pos) {
                float4 yv = yt4[(i * TB + cv) * 20 + chunk];
                y0 = yv.x; y1 = yv.y; y2 = yv.z; y3 = yv.w;
            }
            cls_acc += focal1(y0 != 0.f, l4[0]) + focal1(y1 != 0.f, l4[1]) +
                       focal1(y2 != 0.f, l4[2]) + focal1(y3 != 0.f, l4[3]);
            if (pos && chunk == 0) {
                posc += 1;
                float4 bt = ((const float4*)bbox_true)[i * TB + cv];
                float4 an = ((const float4*)anchors)[a];
                float wa = fmaxf(an.z - an.x, EPSF), ha = fmaxf(an.w - an.y, EPSF);
                float cxa = an.x + 0.5f * wa,  cya = an.y + 0.5f * ha;
                float wt = fmaxf(bt.z - bt.x, EPSF), ht = fmaxf(bt.w - bt.y, EPSF);
                float cxt = bt.x + 0.5f * (bt.z - bt.x), cyt = bt.y + 0.5f * (bt.w - bt.y);
                float d0 = (cxt - cxa) / wa, d1 = (cyt - cya) / ha;
                float d2 = __logf(wt / wa),  d3 = __logf(ht / ha);
                float4 bp = ((const float4*)bbox_pred)[g];
                box_acc += smooth_l1(d0 - bp.x) + smooth_l1(d1 - bp.y) +
                           smooth_l1(d2 - bp.z) + smooth_l1(d3 - bp.w);
            }
        }
    }

    // 64-lane shuffle reduce, then cross-wave via shared, one store per block
    for (int off = 32; off > 0; off >>= 1) {
        cls_acc += __shfl_down(cls_acc, off);
        box_acc += __shfl_down(box_acc, off);
        posc    += __shfl_down(posc, off);
    }
    __shared__ float s_cls[5], s_box[5];
    __shared__ int   s_pc[5];
    int wave = tid >> 6, lane = tid & 63;
    if (lane == 0) { s_cls[wave] = cls_acc; s_box[wave] = box_acc; s_pc[wave] = posc; }
    __syncthreads();
    if (tid == 0) {
        partial_cls[b] = s_cls[0] + s_cls[1] + s_cls[2] + s_cls[3] + s_cls[4];
        partial_box[b] = s_box[0] + s_box[1] + s_box[2] + s_box[3] + s_box[4];
        partial_pos[b] = s_pc[0] + s_pc[1] + s_pc[2] + s_pc[3] + s_pc[4];
    }
}

// ---------------- kernel C: final reduce + divide + sanitize ----------------
// one block, 256 threads. 2048 partials; pos counts are per-batch (256 blocks/batch).
__global__ __launch_bounds__(256) void reduce_kernel(
    const float* __restrict__ partial_cls,
    const float* __restrict__ partial_box,
    const int*   __restrict__ partial_pos,
    float* __restrict__ out)
{
    const int tid = threadIdx.x;
    const int wave = tid >> 6, lane = tid & 63;
    __shared__ double sc[4], sb[4];
    __shared__ int    si[4];
    __shared__ float  s_avg;

    double c = 0.0, bx = 0.0;
    #pragma unroll
    for (int j = 0; j < LOSS_BLOCKS / 256; ++j) {
        c  += (double)partial_cls[tid + j * 256];
        bx += (double)partial_box[tid + j * 256];
    }

    // per-batch positive counts -> avg_factor
    float avg = 0.f;
    for (int bb = 0; bb < NB; ++bb) {
        int p = partial_pos[bb * 256 + tid];
        for (int off = 32; off > 0; off >>= 1) p += __shfl_down(p, off);
        if (lane == 0) si[wave] = p;
        __syncthreads();
        if (tid == 0) {
            int tot = si[0] + si[1] + si[2] + si[3];
            avg += fmaxf((float)tot, 1.0f);
        }
        __syncthreads();
    }
    if (tid == 0) s_avg = avg;

    for (int off = 32; off > 0; off >>= 1) {
        c  += __shfl_down(c, off);
        bx += __shfl_down(bx, off);
    }
    if (lane == 0) { sc[wave] = c; sb[wave] = bx; }
    __syncthreads();
    if (tid == 0) {
        double ct = sc[0] + sc[1] + sc[2] + sc[3];
        double bt = sb[0] + sb[1] + sb[2] + sb[3];
        float cf = (float)(ct / (double)s_avg);
        float bf = (float)(bt / (double)s_avg);
        if (isnan(cf) || isinf(cf)) cf = 0.f;
        if (isnan(bf) || isinf(bf)) bf = 0.f;
        out[0] = cf;
        out[1] = bf;
    }
}

extern "C" void kernel_launch(void* const* d_in, const int* in_sizes, int n_in,
                              void* d_out, int out_size, void* d_ws, size_t ws_size,
                              hipStream_t stream) {
    const float* y_true    = (const float*)d_in[0];
    const float* bbox_true = (const float*)d_in[1];
    const float* y_pred    = (const float*)d_in[2];
    const float* bbox_pred = (const float*)d_in[3];
    const float* anchors   = (const float*)d_in[4];
    float* out = (float*)d_out;

    char* ws = (char*)d_ws;
    unsigned long long* gt_key = (unsigned long long*)ws;
    int*   code        = (int*)(ws + WS_CODE_OFF);
    float* partial_cls = (float*)(ws + WS_PCLS_OFF);
    float* partial_box = (float*)(ws + WS_PBOX_OFF);
    int*   partial_pos = (int*)(ws + WS_PPOS_OFF);

    // zero only gt_key (atomicMax baseline); partials are fully overwritten
    hipMemsetAsync(ws, 0, NB * TB * sizeof(unsigned long long), stream);

    assign_kernel<<<NB * AB / 256, 256, 0, stream>>>(bbox_true, anchors, code, gt_key);
    loss_kernel<<<LOSS_BLOCKS, 320, 0, stream>>>(
        y_true, bbox_true, y_pred, bbox_pred, anchors, code, gt_key,
        partial_cls, partial_box, partial_pos);
    reduce_kernel<<<1, 256, 0, stream>>>(partial_cls, partial_box, partial_pos, out);
}